// Round 5
// baseline (1981.052 us; speedup 1.0000x reference)
//
#include <hip/hip_runtime.h>
#include <hip/hip_bf16.h>

#define DD 32
#define TT 9
#define LL 24
#define HH 8
#define NPOS 216           // TT*LL
#define RPB_W 47           // 2*LL-1
#define ALPHA 0.9f

__device__ __forceinline__ float gelu_exact(float x) {
    return 0.5f * x * (1.0f + erff(x * 0.7071067811865476f));
}
__device__ __forceinline__ float sigmoidf_(float x) { return 1.0f / (1.0f + expf(-x)); }

// ws float layout: [0,1024) a32 ; [1024,1088) wl05 ; [1088,1472) rpm[8][48] ;
// [2048, 2048+B*32) spool (later overwritten with delta) ; then ssq (B*32)

// ---------------- K0: a32 + premixed 0.5*W_logit + premixed rel-pos bias ----------------
__global__ void k0_prep(const float* __restrict__ wcausal,
                        const float* __restrict__ w_logit,
                        const float* __restrict__ rpb,
                        float* __restrict__ ws) {
    __shared__ float A[DD][DD];
    __shared__ float rs[DD];
    int tid = threadIdx.x;              // 1024 threads
    int i = tid >> 5, j = tid & 31;
    float a = (i == j) ? 0.0f : log1pf(expf(wcausal[tid]));
    A[i][j] = a;
    __syncthreads();
    if (j == 0) {
        float s = 0.0f;
        for (int k = 0; k < DD; k++) s += A[i][k];
        rs[i] = ALPHA / (s + 1e-6f);
    }
    __syncthreads();
    ws[tid] = A[i][j] * rs[i];
    if (tid < 64) ws[1024 + tid] = 0.5f * w_logit[tid];
    if (tid < 384) {
        int H = tid / 48, r = tid % 48;
        float v = 0.0f;
        if (r < RPB_W) {
            for (int h = 0; h < HH; h++) v += w_logit[h * HH + H] * rpb[h * RPB_W + r];
        }
        ws[1088 + tid] = v;
    }
}

// ---------------- K1a: per-(b,c) sum / sum-of-squares (memory-bound) ----------------
__global__ __launch_bounds__(256) void k1a(const float* __restrict__ x,
                                           float* __restrict__ sp, float* __restrict__ sq) {
    int b = blockIdx.x, tid = threadIdx.x;
    int c = tid >> 3, r = tid & 7;
    const float4* x4 = (const float4*)(x + (size_t)b * (DD * NPOS) + (size_t)c * NPOS);
    float s = 0.0f, q = 0.0f;
    for (int k = r; k < 54; k += 8) {   // 54 float4 = 216 floats
        float4 v = x4[k];
        s += v.x + v.y + v.z + v.w;
        q += v.x * v.x + v.y * v.y + v.z * v.z + v.w * v.w;
    }
    for (int m = 1; m < 8; m <<= 1) { s += __shfl_xor(s, m); q += __shfl_xor(q, m); }
    if (r == 0) { sp[b * DD + c] = s; sq[b * DD + c] = q; }
}

// ---------------- K1b: one batch element per thread; full chain in registers ----------------
__global__ __launch_bounds__(64) void k1b(
    const float* __restrict__ ln_g, const float* __restrict__ ln_b,
    const float* __restrict__ rp_w1, const float* __restrict__ rp_b1,
    const float* __restrict__ rp_w2, const float* __restrict__ rp_b2,
    const float* __restrict__ mask_w, const float* __restrict__ mask_b,
    const float* __restrict__ val_w1, const float* __restrict__ val_b1,
    const float* __restrict__ val_w2, const float* __restrict__ val_b2,
    const float* __restrict__ fuse_gate, const float* __restrict__ ws,
    float* __restrict__ sp /* in: sums; out: g*delta */, const float* __restrict__ sq)
{
    __shared__ float W[6][1024];   // rp_w1, rp_w2, mask_w, val_w1, val_w2, a32
    __shared__ float V[7][32];     // ln_g, ln_b, rp_b1, rp_b2, mask_b, val_b1, val_b2
    int tid = threadIdx.x;
    for (int idx = tid; idx < 1024; idx += 64) {
        W[0][idx] = rp_w1[idx]; W[1][idx] = rp_w2[idx]; W[2][idx] = mask_w[idx];
        W[3][idx] = val_w1[idx]; W[4][idx] = val_w2[idx]; W[5][idx] = ws[idx];
    }
    if (tid < 32) {
        V[0][tid] = ln_g[tid]; V[1][tid] = ln_b[tid]; V[2][tid] = rp_b1[tid];
        V[3][tid] = rp_b2[tid]; V[4][tid] = mask_b[tid]; V[5][tid] = val_b1[tid];
        V[6][tid] = val_b2[tid];
    }
    __syncthreads();
    int b = blockIdx.x * 64 + tid;

    float pooled[32], scl[32];
    const float4* sp4 = (const float4*)(sp + (size_t)b * 32);
    const float4* sq4 = (const float4*)(sq + (size_t)b * 32);
    #pragma unroll
    for (int k = 0; k < 8; k++) {
        float4 sv = sp4[k], qv = sq4[k];
        float ss[4] = {sv.x, sv.y, sv.z, sv.w};
        float qq[4] = {qv.x, qv.y, qv.z, qv.w};
        #pragma unroll
        for (int m = 0; m < 4; m++) {
            int c = 4 * k + m;
            float p = ss[m] * (1.0f / NPOS);
            pooled[c] = p;
            float var1 = (qq[m] - (float)NPOS * p * p) * (1.0f / (NPOS - 1));
            scl[c] = fmaxf(sqrtf(fmaxf(var1, 0.0f)), 1e-3f);
        }
    }
    float mu = 0.0f;
    #pragma unroll
    for (int c = 0; c < 32; c++) mu += pooled[c];
    mu *= (1.0f / 32.0f);
    float vv = 0.0f;
    #pragma unroll
    for (int c = 0; c < 32; c++) { float d = pooled[c] - mu; vv += d * d; }
    vv *= (1.0f / 32.0f);
    float inv = rsqrtf(vv + 1e-5f);
    float pn[32];
    #pragma unroll
    for (int c = 0; c < 32; c++) pn[c] = (pooled[c] - mu) * inv * V[0][c] + V[1][c];

    float h1[32];
    #pragma unroll
    for (int i = 0; i < 32; i++) {
        float acc = V[2][i];
        #pragma unroll
        for (int j = 0; j < 32; j++) acc += pn[j] * W[0][i * 32 + j];
        h1[i] = gelu_exact(acc);
    }
    float pr[32];
    #pragma unroll
    for (int i = 0; i < 32; i++) {
        float acc = V[3][i];
        #pragma unroll
        for (int j = 0; j < 32; j++) acc += h1[j] * W[1][i * 32 + j];
        pr[i] = acc;
    }
    float g1[32];
    #pragma unroll
    for (int i = 0; i < 32; i++) {
        float acc = V[5][i];
        #pragma unroll
        for (int j = 0; j < 32; j++) acc += pr[j] * W[3][i * 32 + j];
        g1[i] = gelu_exact(acc);
    }
    float xd[32];
    #pragma unroll
    for (int i = 0; i < 32; i++) {
        float am = V[4][i];
        #pragma unroll
        for (int j = 0; j < 32; j++) am += pr[j] * W[2][i * 32 + j];
        float M = sigmoidf_(am);
        float av = V[6][i];
        #pragma unroll
        for (int j = 0; j < 32; j++) av += g1[j] * W[4][i * 32 + j];
        float v32 = tanhf(av) * scl[i] + pooled[i];
        xd[i] = (1.0f - M) * pooled[i] + M * v32;
    }
    float y[32];
    #pragma unroll
    for (int c = 0; c < 32; c++) y[c] = xd[c];
    for (int it = 0; it < 3; it++) {
        float ny[32];
        #pragma unroll
        for (int i = 0; i < 32; i++) {
            float acc = xd[i];
            #pragma unroll
            for (int j = 0; j < 32; j++) acc += y[j] * W[5][i * 32 + j];
            ny[i] = acc;
        }
        #pragma unroll
        for (int c = 0; c < 32; c++) y[c] = ny[c];
    }
    float g = sigmoidf_(fuse_gate[0]);
    float4* dout4 = (float4*)(sp + (size_t)b * 32);
    #pragma unroll
    for (int k = 0; k < 8; k++) {
        float4 o;
        o.x = g * (y[4 * k + 0] - pooled[4 * k + 0]);
        o.y = g * (y[4 * k + 1] - pooled[4 * k + 1]);
        o.z = g * (y[4 * k + 2] - pooled[4 * k + 2]);
        o.w = g * (y[4 * k + 3] - pooled[4 * k + 3]);
        dout4[k] = o;
    }
}

// ---------------- K2: per (b,t) attention ----------------
// LDS-pipe-throughput-bound kernel. This round: 3-row register tiling so each
// LDS weight/logit read feeds 3 FMA rows (cuts cross-wave re-read redundancy).
//  - proj: wave m = matrix (q/k/v); thread (g,q) computes rows g,g+8,g+16.
//  - logits: 64 threads (h,g), 3 rows each; k-row reads amortized x3.
//  - PV: 64 threads (g,q), 3 rows; vsf reads amortized x3.
//  - m_w: 64 threads (g,q), 3 rows; wm reads amortized x3.
// All reads are 8-distinct-address broadcasts or balanced bank spreads.
__global__ __launch_bounds__(192) void k2_attn(
    const float* __restrict__ x,
    const float* __restrict__ ws,        // wl05 @1024, rpm @1088
    const float* __restrict__ delta,
    const float* __restrict__ q_w, const float* __restrict__ q_b,
    const float* __restrict__ k_w, const float* __restrict__ k_b,
    const float* __restrict__ v_w, const float* __restrict__ v_b,
    const float* __restrict__ m_w, const float* __restrict__ m_b,
    const float* __restrict__ w_ctx,
    float* __restrict__ out)
{
    __shared__ float r1[3456];
    __shared__ float r2[5824];
    __shared__ float msc[640];
    float* fusedf = r1;                 // [24][36]
    float* qsf = r1 + 864;
    float* ksf = r1 + 1728;
    float* vsf = r1 + 2592;
    float* wqf = r2;                    // phase A: swizzled transposed [32][32]
    float* wkf = r2 + 1024;
    float* wvf = r2 + 2048;
    float* lg2 = r2;                    // phase C+: [i][j][h], per-i stride 196
    float* wmf = r2 + 4800;             // swizzled transposed [32][32]
    float* bqf = msc, *bkf = msc + 32, *bvf = msc + 64, *bmf = msc + 96;
    float* wl05f = msc + 128;
    float* wcf = msc + 192;
    float* rpmf = msc + 256;            // [8][48]

    int blk = blockIdx.x;
    int b = blk / TT, t = blk % TT;
    int tid = threadIdx.x;

    // ---- stage ----
    for (int idx = tid; idx < 768; idx += 192) {   // q/k/v weights, transposed + swizzled
        int m = idx >> 8, r = idx & 255;
        int i = r >> 3, jq = r & 7;
        const float* src = (m == 0) ? q_w : (m == 1) ? k_w : v_w;
        float* dst = (m == 0) ? wqf : (m == 1) ? wkf : wvf;
        float4 v = ((const float4*)src)[r];
        int col = i ^ (4 * jq);
        dst[(4 * jq + 0) * 32 + col] = v.x;
        dst[(4 * jq + 1) * 32 + col] = v.y;
        dst[(4 * jq + 2) * 32 + col] = v.z;
        dst[(4 * jq + 3) * 32 + col] = v.w;
    }
    if (tid < 32) { bqf[tid] = q_b[tid]; bkf[tid] = k_b[tid]; bvf[tid] = v_b[tid]; bmf[tid] = m_b[tid]; }
    else if (tid < 96) wl05f[tid - 32] = ws[1024 + tid - 32];
    else if (tid < 160) wcf[tid - 96] = w_ctx[tid - 96];
    for (int idx = tid; idx < 384; idx += 192) rpmf[idx] = ws[1088 + idx];
    {                                   // fused[l][c] = x + delta (all 192 threads)
        int c = tid / 6, k = tid % 6;
        const float4* p = (const float4*)(x + (size_t)b * (DD * NPOS) + (size_t)c * NPOS + t * LL);
        float4 v = p[k];
        float gd = delta[b * DD + c];
        int l0 = 4 * k;
        fusedf[(l0 + 0) * 36 + c] = v.x + gd;
        fusedf[(l0 + 1) * 36 + c] = v.y + gd;
        fusedf[(l0 + 2) * 36 + c] = v.z + gd;
        fusedf[(l0 + 3) * 36 + c] = v.w + gd;
    }
    __syncthreads();

    // ---- q/k/v projection: wave = matrix, thread (g,q) -> rows g, g+8, g+16 ----
    {
        int m = tid >> 6;               // 0,1,2 (one wave per matrix)
        int g = (tid >> 3) & 7, q = tid & 7;
        const float* wmat = (m == 0) ? wqf : (m == 1) ? wkf : wvf;
        const float* bias = (m == 0) ? bqf : (m == 1) ? bkf : bvf;
        float* dst       = (m == 0) ? qsf : (m == 1) ? ksf : vsf;
        float4 bq = *(const float4*)&bias[4 * q];
        float4 a0 = bq, a1 = bq, a2 = bq;
        #pragma unroll
        for (int jq = 0; jq < 8; jq++) {
            float4 f0 = *(const float4*)&fusedf[(g + 0) * 36 + 4 * jq];
            float4 f1 = *(const float4*)&fusedf[(g + 8) * 36 + 4 * jq];
            float4 f2 = *(const float4*)&fusedf[(g + 16) * 36 + 4 * jq];
            float f0v[4] = {f0.x, f0.y, f0.z, f0.w};
            float f1v[4] = {f1.x, f1.y, f1.z, f1.w};
            float f2v[4] = {f2.x, f2.y, f2.z, f2.w};
            #pragma unroll
            for (int jj = 0; jj < 4; jj++) {
                int j = 4 * jq + jj;
                int sw = (4 * q) ^ (j & 28);
                float4 w = *(const float4*)&wmat[j * 32 + sw];
                a0.x += f0v[jj] * w.x; a0.y += f0v[jj] * w.y; a0.z += f0v[jj] * w.z; a0.w += f0v[jj] * w.w;
                a1.x += f1v[jj] * w.x; a1.y += f1v[jj] * w.y; a1.z += f1v[jj] * w.z; a1.w += f1v[jj] * w.w;
                a2.x += f2v[jj] * w.x; a2.y += f2v[jj] * w.y; a2.z += f2v[jj] * w.z; a2.w += f2v[jj] * w.w;
            }
        }
        float n0 = 1.0f / fmaxf(sqrtf(a0.x*a0.x + a0.y*a0.y + a0.z*a0.z + a0.w*a0.w), 1e-12f);
        float n1 = 1.0f / fmaxf(sqrtf(a1.x*a1.x + a1.y*a1.y + a1.z*a1.z + a1.w*a1.w), 1e-12f);
        float n2 = 1.0f / fmaxf(sqrtf(a2.x*a2.x + a2.y*a2.y + a2.z*a2.z + a2.w*a2.w), 1e-12f);
        a0.x *= n0; a0.y *= n0; a0.z *= n0; a0.w *= n0;
        a1.x *= n1; a1.y *= n1; a1.z *= n1; a1.w *= n1;
        a2.x *= n2; a2.y *= n2; a2.z *= n2; a2.w *= n2;
        *(float4*)&dst[(g + 0) * 36 + 4 * q] = a0;
        *(float4*)&dst[(g + 8) * 36 + 4 * q] = a1;
        *(float4*)&dst[(g + 16) * 36 + 4 * q] = a2;
    }
    __syncthreads();

    // ---- stage wm (r2 tail; wq/wk/wv dead) + raw logits into lg2[i][j][h] ----
    for (int idx = tid; idx < 256; idx += 192) {   // 256 float4 = whole m_w
        int i = idx >> 3, jq = idx & 7;
        float4 v = ((const float4*)m_w)[idx];
        int col = i ^ (4 * jq);
        wmf[(4 * jq + 0) * 32 + col] = v.x;
        wmf[(4 * jq + 1) * 32 + col] = v.y;
        wmf[(4 * jq + 2) * 32 + col] = v.z;
        wmf[(4 * jq + 3) * 32 + col] = v.w;
    }
    if (tid < 64) {                     // thread (h,g): 3 logit rows i = g, g+8, g+16
        int h = tid & 7, g = tid >> 3;
        float4 q0 = *(const float4*)&qsf[(g + 0) * 36 + 4 * h];
        float4 q1 = *(const float4*)&qsf[(g + 8) * 36 + 4 * h];
        float4 q2 = *(const float4*)&qsf[(g + 16) * 36 + 4 * h];
        #pragma unroll
        for (int j = 0; j < 24; j++) {
            float4 k4 = *(const float4*)&ksf[j * 36 + 4 * h];
            lg2[(g + 0) * 196 + j * 8 + h] = q0.x * k4.x + q0.y * k4.y + q0.z * k4.z + q0.w * k4.w;
            lg2[(g + 8) * 196 + j * 8 + h] = q1.x * k4.x + q1.y * k4.y + q1.z * k4.z + q1.w * k4.w;
            lg2[(g + 16) * 196 + j * 8 + h] = q2.x * k4.x + q2.y * k4.y + q2.z * k4.z + q2.w * k4.w;
        }
    }
    __syncthreads();

    // ---- fused W_logit mix + rel-pos bias + softmax (registers) ----
    // thread = (H = tid&7, i = tid>>3); reads all-h rows as 2x b128
    float sm[24];
    {
        {
            int H = tid & 7, i = tid >> 3;
            float wlc[8];
            #pragma unroll
            for (int h = 0; h < 8; h++) wlc[h] = wl05f[h * 8 + H];
            float mx = -1e30f;
            #pragma unroll
            for (int j = 0; j < 24; j++) {
                float4 ta = *(const float4*)&lg2[i * 196 + j * 8];
                float4 tb = *(const float4*)&lg2[i * 196 + j * 8 + 4];
                float a = rpmf[H * 48 + (i - j + 23)];
                a += ta.x * wlc[0] + ta.y * wlc[1] + ta.z * wlc[2] + ta.w * wlc[3]
                   + tb.x * wlc[4] + tb.y * wlc[5] + tb.z * wlc[6] + tb.w * wlc[7];
                sm[j] = a;
                mx = fmaxf(mx, a);
            }
            float s = 0.0f;
            #pragma unroll
            for (int j = 0; j < 24; j++) { float e = __expf(sm[j] - mx); sm[j] = e; s += e; }
            float inv = 1.0f / s;
            #pragma unroll
            for (int j = 0; j < 24; j++) sm[j] *= inv;
        }
        __syncthreads();                 // all reads of raw logits done before overwrite
        {
            int H = tid & 7, i = tid >> 3;
            #pragma unroll
            for (int j = 0; j < 24; j++) lg2[i * 196 + j * 8 + H] = sm[j];
        }
    }
    __syncthreads();

    // ---- fused W_ctx mix + PV: 64 threads (g,q), 3 rows; vsf amortized x3 ----
    if (tid < 64) {
        int g = tid >> 3, q = tid & 7;
        float wcc[8];
        #pragma unroll
        for (int h = 0; h < 8; h++) wcc[h] = wcf[h * 8 + q];
        float4 a0 = {0,0,0,0}, a1 = {0,0,0,0}, a2 = {0,0,0,0};
        #pragma unroll
        for (int j = 0; j < 24; j++) {
            float4 v4 = *(const float4*)&vsf[j * 36 + 4 * q];
            float4 ta0 = *(const float4*)&lg2[(g + 0) * 196 + j * 8];
            float4 tb0 = *(const float4*)&lg2[(g + 0) * 196 + j * 8 + 4];
            float4 ta1 = *(const float4*)&lg2[(g + 8) * 196 + j * 8];
            float4 tb1 = *(const float4*)&lg2[(g + 8) * 196 + j * 8 + 4];
            float4 ta2 = *(const float4*)&lg2[(g + 16) * 196 + j * 8];
            float4 tb2 = *(const float4*)&lg2[(g + 16) * 196 + j * 8 + 4];
            float m0 = ta0.x*wcc[0] + ta0.y*wcc[1] + ta0.z*wcc[2] + ta0.w*wcc[3]
                     + tb0.x*wcc[4] + tb0.y*wcc[5] + tb0.z*wcc[6] + tb0.w*wcc[7];
            float m1 = ta1.x*wcc[0] + ta1.y*wcc[1] + ta1.z*wcc[2] + ta1.w*wcc[3]
                     + tb1.x*wcc[4] + tb1.y*wcc[5] + tb1.z*wcc[6] + tb1.w*wcc[7];
            float m2 = ta2.x*wcc[0] + ta2.y*wcc[1] + ta2.z*wcc[2] + ta2.w*wcc[3]
                     + tb2.x*wcc[4] + tb2.y*wcc[5] + tb2.z*wcc[6] + tb2.w*wcc[7];
            a0.x += m0 * v4.x; a0.y += m0 * v4.y; a0.z += m0 * v4.z; a0.w += m0 * v4.w;
            a1.x += m1 * v4.x; a1.y += m1 * v4.y; a1.z += m1 * v4.z; a1.w += m1 * v4.w;
            a2.x += m2 * v4.x; a2.y += m2 * v4.y; a2.z += m2 * v4.z; a2.w += m2 * v4.w;
        }
        *(float4*)&fusedf[(g + 0) * 36 + 4 * q] = a0;
        *(float4*)&fusedf[(g + 8) * 36 + 4 * q] = a1;
        *(float4*)&fusedf[(g + 16) * 36 + 4 * q] = a2;
    }
    __syncthreads();

    // ---- m_w projection: 64 threads (g,q), 3 rows -> res[c][l] (stride 25) ----
    if (tid < 64) {
        int g = tid >> 3, q = tid & 7;
        float4 bq = *(const float4*)&bmf[4 * q];
        float4 a0 = bq, a1 = bq, a2 = bq;
        #pragma unroll
        for (int cq = 0; cq < 8; cq++) {
            float4 f0 = *(const float4*)&fusedf[(g + 0) * 36 + 4 * cq];
            float4 f1 = *(const float4*)&fusedf[(g + 8) * 36 + 4 * cq];
            float4 f2 = *(const float4*)&fusedf[(g + 16) * 36 + 4 * cq];
            float f0v[4] = {f0.x, f0.y, f0.z, f0.w};
            float f1v[4] = {f1.x, f1.y, f1.z, f1.w};
            float f2v[4] = {f2.x, f2.y, f2.z, f2.w};
            #pragma unroll
            for (int cc = 0; cc < 4; cc++) {
                int c = 4 * cq + cc;
                int sw = (4 * q) ^ (c & 28);
                float4 w4 = *(const float4*)&wmf[c * 32 + sw];
                a0.x += f0v[cc] * w4.x; a0.y += f0v[cc] * w4.y; a0.z += f0v[cc] * w4.z; a0.w += f0v[cc] * w4.w;
                a1.x += f1v[cc] * w4.x; a1.y += f1v[cc] * w4.y; a1.z += f1v[cc] * w4.z; a1.w += f1v[cc] * w4.w;
                a2.x += f2v[cc] * w4.x; a2.y += f2v[cc] * w4.y; a2.z += f2v[cc] * w4.z; a2.w += f2v[cc] * w4.w;
            }
        }
        float* resf = qsf;
        float av0[4] = {a0.x, a0.y, a0.z, a0.w};
        float av1[4] = {a1.x, a1.y, a1.z, a1.w};
        float av2[4] = {a2.x, a2.y, a2.z, a2.w};
        #pragma unroll
        for (int e = 0; e < 4; e++) {
            resf[(4 * q + e) * 25 + (g + 0)]  = av0[e];
            resf[(4 * q + e) * 25 + (g + 8)]  = av1[e];
            resf[(4 * q + e) * 25 + (g + 16)] = av2[e];
        }
    }
    __syncthreads();

    // ---- coalesced global write ----
    {
        const float* resf = qsf;
        int c = tid / 6, k = tid - c * 6;
        float4 v;
        v.x = resf[c * 25 + 4 * k + 0];
        v.y = resf[c * 25 + 4 * k + 1];
        v.z = resf[c * 25 + 4 * k + 2];
        v.w = resf[c * 25 + 4 * k + 3];
        float4* o4 = (float4*)(out + (size_t)b * (DD * NPOS) + (size_t)c * NPOS + t * LL);
        o4[k] = v;
    }
}

// ---------------- K3: prediction branch (256 threads: staging needs the 4th wave) ----------------
__global__ __launch_bounds__(256) void k3_pred(
    const float* __restrict__ pre_prompt,
    const float* __restrict__ conv_w, const float* __restrict__ conv_b,
    const float* __restrict__ p_w, const float* __restrict__ p_b,
    float* __restrict__ out)
{
    __shared__ float conf[DD * NPOS];            // 6912 floats
    __shared__ __hip_bfloat16 cwh[DD * 324];     // [co][ci*10+tt], per-co stride 324 (320 used)
    __shared__ float pbuff[DD * 25];             // [co][l] stride 25
    __shared__ __hip_bfloat16 pwh[24 * 28];      // [l_out][l_in], row stride 28 (24 used)
    __shared__ float pbv[24], cbv[32];
    int b = blockIdx.x, tid = threadIdx.x;

    const float4* o4 = (const float4*)(out + (size_t)b * (DD * NPOS));
    for (int idx = tid; idx < 1728; idx += 256) {
        int flat = idx * 4;
        int t = (flat % NPOS) / LL;              // uniform within the float4
        float4 v;
        if (t < 8) {
            v = o4[idx];
        } else {
            int c = flat / NPOS, l = flat % LL;  // 192 % 24 == 0
            v = ((const float4*)pre_prompt)[(c * LL + l) >> 2];
        }
        *(float4*)&conf[flat] = v;               // contiguous b128 store: conflict-free
    }
    for (int idx = tid; idx < 2304; idx += 256) {
        float4 v = ((const float4*)conv_w)[idx];
        int flat = idx * 4;
        float vv[4] = {v.x, v.y, v.z, v.w};
        #pragma unroll
        for (int e = 0; e < 4; e++) {
            int f = flat + e;
            int co = f / 288, r = f - co * 288;
            int ci = r / 9, ttt = r - ci * 9;
            cwh[co * 324 + ci * 10 + ttt] = __float2bfloat16(vv[e]);
        }
    }
    for (int idx = tid; idx < 144; idx += 256) {
        float4 v = ((const float4*)p_w)[idx];
        int flat = idx * 4;
        float vv[4] = {v.x, v.y, v.z, v.w};
        #pragma unroll
        for (int e = 0; e < 4; e++) {
            int f = flat + e;
            int row = f / 24, col = f - row * 24;
            pwh[row * 28 + col] = __float2bfloat16(vv[e]);
        }
    }
    if (tid < 24) pbv[tid] = p_b[tid];
    if (tid >= 32 && tid < 64) cbv[tid - 32] = conv_b[tid - 32];
    __syncthreads();

    // conv over contexts: thread = (co, l-quad)
    if (tid < 192) {
        int co = tid / 6, ql = tid - co * 6;
        float cb = cbv[co];
        float4 acc = {cb, cb, cb, cb};
        const float4* cf4 = (const float4*)conf;    // [ci][tt][ql] -> ci*54 + tt*6 + ql
        for (int ci = 0; ci < 32; ci++) {
            const uint32_t* wp = (const uint32_t*)&cwh[co * 324 + ci * 10];
            #pragma unroll
            for (int p = 0; p < 4; p++) {
                uint32_t u = wp[p];
                float w0 = __uint_as_float(u << 16);
                float w1 = __uint_as_float(u & 0xffff0000u);
                float4 v0 = cf4[ci * 54 + (2 * p) * 6 + ql];
                float4 v1 = cf4[ci * 54 + (2 * p + 1) * 6 + ql];
                acc.x += w0 * v0.x + w1 * v1.x;
                acc.y += w0 * v0.y + w1 * v1.y;
                acc.z += w0 * v0.z + w1 * v1.z;
                acc.w += w0 * v0.w + w1 * v1.w;
            }
            float w8 = __bfloat162float(cwh[co * 324 + ci * 10 + 8]);
            float4 v8 = cf4[ci * 54 + 48 + ql];
            acc.x += w8 * v8.x; acc.y += w8 * v8.y; acc.z += w8 * v8.z; acc.w += w8 * v8.w;
        }
        pbuff[co * 25 + 4 * ql + 0] = fmaxf(acc.x, 0.0f);
        pbuff[co * 25 + 4 * ql + 1] = fmaxf(acc.y, 0.0f);
        pbuff[co * 25 + 4 * ql + 2] = fmaxf(acc.z, 0.0f);
        pbuff[co * 25 + 4 * ql + 3] = fmaxf(acc.w, 0.0f);
    }
    __syncthreads();

    // token linear + subtraction into the t=8 plane
    if (tid < 192) {
        int c = tid / 6, ql = tid - c * 6;
        float accv[4] = {pbv[4 * ql + 0], pbv[4 * ql + 1], pbv[4 * ql + 2], pbv[4 * ql + 3]};
        #pragma unroll
        for (int lp = 0; lp < 24; lp += 2) {
            float pv0 = pbuff[c * 25 + lp];
            float pv1 = pbuff[c * 25 + lp + 1];
            #pragma unroll
            for (int e = 0; e < 4; e++) {
                uint32_t u = *(const uint32_t*)&pwh[(4 * ql + e) * 28 + lp];
                accv[e] += pv0 * __uint_as_float(u << 16) + pv1 * __uint_as_float(u & 0xffff0000u);
            }
        }
        float4* op = (float4*)(out + (size_t)b * (DD * NPOS) + (size_t)c * NPOS + 8 * LL);
        float4 xa = op[ql];
        float4 r;
        r.x = xa.x - accv[0]; r.y = xa.y - accv[1]; r.z = xa.z - accv[2]; r.w = xa.w - accv[3];
        op[ql] = r;
    }
}

extern "C" void kernel_launch(void* const* d_in, const int* in_sizes, int n_in,
                              void* d_out, int out_size, void* d_ws, size_t ws_size,
                              hipStream_t stream) {
    const float* x        = (const float*)d_in[0];
    const float* ln_g     = (const float*)d_in[1];
    const float* ln_b     = (const float*)d_in[2];
    const float* rp_w1    = (const float*)d_in[3];
    const float* rp_b1    = (const float*)d_in[4];
    const float* rp_w2    = (const float*)d_in[5];
    const float* rp_b2    = (const float*)d_in[6];
    const float* W_causal = (const float*)d_in[7];
    const float* mask_w   = (const float*)d_in[8];
    const float* mask_b   = (const float*)d_in[9];
    const float* val_w1   = (const float*)d_in[10];
    const float* val_b1   = (const float*)d_in[11];
    const float* val_w2   = (const float*)d_in[12];
    const float* val_b2   = (const float*)d_in[13];
    const float* fuse_g   = (const float*)d_in[14];
    const float* q_w      = (const float*)d_in[15];
    const float* q_b      = (const float*)d_in[16];
    const float* k_w      = (const float*)d_in[17];
    const float* k_b      = (const float*)d_in[18];
    const float* v_w      = (const float*)d_in[19];
    const float* v_b      = (const float*)d_in[20];
    const float* m_w      = (const float*)d_in[21];
    const float* m_b      = (const float*)d_in[22];
    const float* W_logit  = (const float*)d_in[23];
    const float* W_ctx    = (const float*)d_in[24];
    const float* rel_pb   = (const float*)d_in[25];
    const float* pre_pr   = (const float*)d_in[26];
    const float* conv_w   = (const float*)d_in[27];
    const float* conv_b   = (const float*)d_in[28];
    const float* p_w      = (const float*)d_in[29];
    const float* p_b      = (const float*)d_in[30];
    float* out = (float*)d_out;

    int B = in_sizes[0] / (DD * NPOS);

    float* ws = (float*)d_ws;
    float* sp = ws + 2048;            // B*32 sums, then overwritten with g*delta
    float* sq = sp + (size_t)B * 32;  // B*32 sum-of-squares

    hipLaunchKernelGGL(k0_prep, dim3(1), dim3(1024), 0, stream, W_causal, W_logit, rel_pb, ws);
    hipLaunchKernelGGL(k1a, dim3(B), dim3(256), 0, stream, x, sp, sq);
    hipLaunchKernelGGL(k1b, dim3(B / 64), dim3(64), 0, stream,
                       ln_g, ln_b, rp_w1, rp_b1, rp_w2, rp_b2,
                       mask_w, mask_b, val_w1, val_b1, val_w2, val_b2,
                       fuse_g, ws, sp, sq);
    hipLaunchKernelGGL(k2_attn, dim3(B * TT), dim3(192), 0, stream,
                       x, ws, sp, q_w, q_b, k_w, k_b, v_w, v_b, m_w, m_b,
                       W_ctx, out);
    hipLaunchKernelGGL(k3_pred, dim3(B), dim3(256), 0, stream,
                       pre_pr, conv_w, conv_b, p_w, p_b, out);
}

// Round 6
// 1023.188 us; speedup vs baseline: 1.9362x; 1.9362x over previous
//
#include <hip/hip_runtime.h>
#include <hip/hip_bf16.h>

#define DD 32
#define TT 9
#define LL 24
#define HH 8
#define NPOS 216           // TT*LL
#define RPB_W 47           // 2*LL-1
#define ALPHA 0.9f

__device__ __forceinline__ float gelu_exact(float x) {
    return 0.5f * x * (1.0f + erff(x * 0.7071067811865476f));
}
__device__ __forceinline__ float sigmoidf_(float x) { return 1.0f / (1.0f + expf(-x)); }
__device__ __forceinline__ void bf2(uint32_t u, float& lo, float& hi) {
    lo = __uint_as_float(u << 16);
    hi = __uint_as_float(u & 0xffff0000u);
}

// ws float layout: [0,1024) a32 ; [1024,1088) wl05 ; [1088,1472) rpm[8][48] ;
// [1536,2560) q_w^T swz ; [2560,3584) k_w^T swz ; [3584,4608) v_w^T swz ;
// [4608,5632) m_w^T swz ; [8192, 8192+B*32) spool/delta ; then ssq (B*32)

// ---------------- K0: a32 + premixed W_logit/rel-pos + pre-transposed weights ----------------
__global__ void k0_prep(const float* __restrict__ wcausal,
                        const float* __restrict__ w_logit,
                        const float* __restrict__ rpb,
                        const float* __restrict__ q_w, const float* __restrict__ k_w,
                        const float* __restrict__ v_w, const float* __restrict__ m_w,
                        float* __restrict__ ws) {
    __shared__ float A[DD][DD];
    __shared__ float rs[DD];
    int tid = threadIdx.x;              // 1024 threads
    int i = tid >> 5, j = tid & 31;
    float a = (i == j) ? 0.0f : log1pf(expf(wcausal[tid]));
    A[i][j] = a;
    __syncthreads();
    if (j == 0) {
        float s = 0.0f;
        for (int k = 0; k < DD; k++) s += A[i][k];
        rs[i] = ALPHA / (s + 1e-6f);
    }
    __syncthreads();
    ws[tid] = A[i][j] * rs[i];
    if (tid < 64) ws[1024 + tid] = 0.5f * w_logit[tid];
    if (tid < 384) {
        int H = tid / 48, r = tid % 48;
        float v = 0.0f;
        if (r < RPB_W) {
            for (int h = 0; h < HH; h++) v += w_logit[h * HH + H] * rpb[h * RPB_W + r];
        }
        ws[1088 + tid] = v;
    }
    // pre-transpose + XOR-swizzle: dst[j*32 + (i ^ (j&28))] = w[i*32 + j]
    {
        int dsti = j * 32 + (i ^ (j & 28));
        ws[1536 + dsti] = q_w[tid];
        ws[2560 + dsti] = k_w[tid];
        ws[3584 + dsti] = v_w[tid];
        ws[4608 + dsti] = m_w[tid];
    }
}

// ---------------- K1a: per-(b,c) sum / sum-of-squares (memory-bound) ----------------
__global__ __launch_bounds__(256) void k1a(const float* __restrict__ x,
                                           float* __restrict__ sp, float* __restrict__ sq) {
    int b = blockIdx.x, tid = threadIdx.x;
    int c = tid >> 3, r = tid & 7;
    const float4* x4 = (const float4*)(x + (size_t)b * (DD * NPOS) + (size_t)c * NPOS);
    float s = 0.0f, q = 0.0f;
    for (int k = r; k < 54; k += 8) {   // 54 float4 = 216 floats
        float4 v = x4[k];
        s += v.x + v.y + v.z + v.w;
        q += v.x * v.x + v.y * v.y + v.z * v.z + v.w * v.w;
    }
    for (int m = 1; m < 8; m <<= 1) { s += __shfl_xor(s, m); q += __shfl_xor(q, m); }
    if (r == 0) { sp[b * DD + c] = s; sq[b * DD + c] = q; }
}

// ---------------- K1b: one batch element per thread; full chain in registers ----------------
__global__ __launch_bounds__(64) void k1b(
    const float* __restrict__ ln_g, const float* __restrict__ ln_b,
    const float* __restrict__ rp_w1, const float* __restrict__ rp_b1,
    const float* __restrict__ rp_w2, const float* __restrict__ rp_b2,
    const float* __restrict__ mask_w, const float* __restrict__ mask_b,
    const float* __restrict__ val_w1, const float* __restrict__ val_b1,
    const float* __restrict__ val_w2, const float* __restrict__ val_b2,
    const float* __restrict__ fuse_gate, const float* __restrict__ ws,
    float* __restrict__ sp /* in: sums; out: g*delta */, const float* __restrict__ sq)
{
    __shared__ float W[6][1024];   // rp_w1, rp_w2, mask_w, val_w1, val_w2, a32
    __shared__ float V[7][32];     // ln_g, ln_b, rp_b1, rp_b2, mask_b, val_b1, val_b2
    int tid = threadIdx.x;
    for (int idx = tid; idx < 1024; idx += 64) {
        W[0][idx] = rp_w1[idx]; W[1][idx] = rp_w2[idx]; W[2][idx] = mask_w[idx];
        W[3][idx] = val_w1[idx]; W[4][idx] = val_w2[idx]; W[5][idx] = ws[idx];
    }
    if (tid < 32) {
        V[0][tid] = ln_g[tid]; V[1][tid] = ln_b[tid]; V[2][tid] = rp_b1[tid];
        V[3][tid] = rp_b2[tid]; V[4][tid] = mask_b[tid]; V[5][tid] = val_b1[tid];
        V[6][tid] = val_b2[tid];
    }
    __syncthreads();
    int b = blockIdx.x * 64 + tid;

    float pooled[32], scl[32];
    const float4* sp4 = (const float4*)(sp + (size_t)b * 32);
    const float4* sq4 = (const float4*)(sq + (size_t)b * 32);
    #pragma unroll
    for (int k = 0; k < 8; k++) {
        float4 sv = sp4[k], qv = sq4[k];
        float ss[4] = {sv.x, sv.y, sv.z, sv.w};
        float qq[4] = {qv.x, qv.y, qv.z, qv.w};
        #pragma unroll
        for (int m = 0; m < 4; m++) {
            int c = 4 * k + m;
            float p = ss[m] * (1.0f / NPOS);
            pooled[c] = p;
            float var1 = (qq[m] - (float)NPOS * p * p) * (1.0f / (NPOS - 1));
            scl[c] = fmaxf(sqrtf(fmaxf(var1, 0.0f)), 1e-3f);
        }
    }
    float mu = 0.0f;
    #pragma unroll
    for (int c = 0; c < 32; c++) mu += pooled[c];
    mu *= (1.0f / 32.0f);
    float vv = 0.0f;
    #pragma unroll
    for (int c = 0; c < 32; c++) { float d = pooled[c] - mu; vv += d * d; }
    vv *= (1.0f / 32.0f);
    float inv = rsqrtf(vv + 1e-5f);
    float pn[32];
    #pragma unroll
    for (int c = 0; c < 32; c++) pn[c] = (pooled[c] - mu) * inv * V[0][c] + V[1][c];

    float h1[32];
    #pragma unroll
    for (int i = 0; i < 32; i++) {
        float acc = V[2][i];
        #pragma unroll
        for (int j = 0; j < 32; j++) acc += pn[j] * W[0][i * 32 + j];
        h1[i] = gelu_exact(acc);
    }
    float pr[32];
    #pragma unroll
    for (int i = 0; i < 32; i++) {
        float acc = V[3][i];
        #pragma unroll
        for (int j = 0; j < 32; j++) acc += h1[j] * W[1][i * 32 + j];
        pr[i] = acc;
    }
    float g1[32];
    #pragma unroll
    for (int i = 0; i < 32; i++) {
        float acc = V[5][i];
        #pragma unroll
        for (int j = 0; j < 32; j++) acc += pr[j] * W[3][i * 32 + j];
        g1[i] = gelu_exact(acc);
    }
    float xd[32];
    #pragma unroll
    for (int i = 0; i < 32; i++) {
        float am = V[4][i];
        #pragma unroll
        for (int j = 0; j < 32; j++) am += pr[j] * W[2][i * 32 + j];
        float M = sigmoidf_(am);
        float av = V[6][i];
        #pragma unroll
        for (int j = 0; j < 32; j++) av += g1[j] * W[4][i * 32 + j];
        float v32 = tanhf(av) * scl[i] + pooled[i];
        xd[i] = (1.0f - M) * pooled[i] + M * v32;
    }
    float y[32];
    #pragma unroll
    for (int c = 0; c < 32; c++) y[c] = xd[c];
    for (int it = 0; it < 3; it++) {
        float ny[32];
        #pragma unroll
        for (int i = 0; i < 32; i++) {
            float acc = xd[i];
            #pragma unroll
            for (int j = 0; j < 32; j++) acc += y[j] * W[5][i * 32 + j];
            ny[i] = acc;
        }
        #pragma unroll
        for (int c = 0; c < 32; c++) y[c] = ny[c];
    }
    float g = sigmoidf_(fuse_gate[0]);
    float4* dout4 = (float4*)(sp + (size_t)b * 32);
    #pragma unroll
    for (int k = 0; k < 8; k++) {
        float4 o;
        o.x = g * (y[4 * k + 0] - pooled[4 * k + 0]);
        o.y = g * (y[4 * k + 1] - pooled[4 * k + 1]);
        o.z = g * (y[4 * k + 2] - pooled[4 * k + 2]);
        o.w = g * (y[4 * k + 3] - pooled[4 * k + 3]);
        dout4[k] = o;
    }
}

// ---------------- K2: per (b,t) attention ----------------
// LDS-BYTE-bandwidth-bound kernel. This round: (a) weights pre-transposed in k0,
// staged via linear b128 copies; (b) logits/attention array in PACKED BF16
// [i][j][h] (i-stride 100 u32, j-stride 4 u32): mix1/PV read ONE b128 per j.
// LDS total 30.2KB -> 5 blocks/CU.
// r1 = fused/qs/ks/vs [24][36] (3456). r2: phase A wq|wk|wv [32][32] swz (3072);
// phase C+ lg (2400 u32 bf16-packed) + wm swz at 2432.
__global__ __launch_bounds__(256) void k2_attn(
    const float* __restrict__ x,
    const float* __restrict__ ws,        // wl05 @1024, rpm @1088, weights @1536
    const float* __restrict__ delta,
    const float* __restrict__ q_b, const float* __restrict__ k_b,
    const float* __restrict__ v_b, const float* __restrict__ m_b,
    const float* __restrict__ w_ctx,
    float* __restrict__ out)
{
    __shared__ float r1[3456];
    __shared__ float r2[3456];
    __shared__ float msc[640];
    float* fusedf = r1;                 // [24][36]
    float* qsf = r1 + 864;
    float* ksf = r1 + 1728;
    float* vsf = r1 + 2592;
    float* wqf = r2;                    // phase A: swizzled transposed [32][32]
    float* wkf = r2 + 1024;
    float* wvf = r2 + 2048;
    uint32_t* lgu = (uint32_t*)r2;      // phase C+: [i][j][h] bf16-packed, i-stride 100 u32
    __hip_bfloat16* lgh = (__hip_bfloat16*)r2;  // same region, bf16 view (i-stride 200)
    float* wmf = r2 + 2432;             // swizzled transposed [32][32]
    float* bqf = msc, *bkf = msc + 32, *bvf = msc + 64, *bmf = msc + 96;
    float* wl05f = msc + 128;
    float* wcf = msc + 192;
    float* rpmf = msc + 256;            // [8][48]

    int blk = blockIdx.x;
    int b = blk / TT, t = blk % TT;
    int tid = threadIdx.x;

    // ---- stage (weights already transposed+swizzled in ws: linear b128 copy) ----
    for (int idx = tid; idx < 768; idx += 256) {
        float4 v = ((const float4*)(ws + 1536))[idx];
        *(float4*)&r2[idx * 4] = v;
    }
    if (tid < 32) { bqf[tid] = q_b[tid]; bkf[tid] = k_b[tid]; bvf[tid] = v_b[tid]; bmf[tid] = m_b[tid]; }
    else if (tid < 96) wl05f[tid - 32] = ws[1024 + tid - 32];
    else if (tid < 160) wcf[tid - 96] = w_ctx[tid - 96];
    for (int idx = tid; idx < 384; idx += 256) rpmf[idx] = ws[1088 + idx];
    if (tid < 192) {                    // fused[l][c] = x + delta
        int c = tid / 6, k = tid % 6;
        const float4* p = (const float4*)(x + (size_t)b * (DD * NPOS) + (size_t)c * NPOS + t * LL);
        float4 v = p[k];
        float gd = delta[b * DD + c];
        int l0 = 4 * k;
        fusedf[(l0 + 0) * 36 + c] = v.x + gd;
        fusedf[(l0 + 1) * 36 + c] = v.y + gd;
        fusedf[(l0 + 2) * 36 + c] = v.z + gd;
        fusedf[(l0 + 3) * 36 + c] = v.w + gd;
    }
    __syncthreads();

    // ---- q/k/v projection: thread = (l, head q); f rows read as b128 ----
    if (tid < 192) {
        int l = tid >> 3, q = tid & 7;
        float4 aq = *(const float4*)&bqf[4 * q];
        float4 ak = *(const float4*)&bkf[4 * q];
        float4 av = *(const float4*)&bvf[4 * q];
        #pragma unroll
        for (int jq = 0; jq < 8; jq++) {
            float4 f4 = *(const float4*)&fusedf[l * 36 + 4 * jq];
            float fv[4] = {f4.x, f4.y, f4.z, f4.w};
            #pragma unroll
            for (int jj = 0; jj < 4; jj++) {
                int j = 4 * jq + jj;
                int sw = (4 * q) ^ (j & 28);
                float f = fv[jj];
                float4 w0 = *(const float4*)&wqf[j * 32 + sw];
                float4 w1 = *(const float4*)&wkf[j * 32 + sw];
                float4 w2 = *(const float4*)&wvf[j * 32 + sw];
                aq.x += f * w0.x; aq.y += f * w0.y; aq.z += f * w0.z; aq.w += f * w0.w;
                ak.x += f * w1.x; ak.y += f * w1.y; ak.z += f * w1.z; ak.w += f * w1.w;
                av.x += f * w2.x; av.y += f * w2.y; av.z += f * w2.z; av.w += f * w2.w;
            }
        }
        float nq = 1.0f / fmaxf(sqrtf(aq.x*aq.x + aq.y*aq.y + aq.z*aq.z + aq.w*aq.w), 1e-12f);
        float nk = 1.0f / fmaxf(sqrtf(ak.x*ak.x + ak.y*ak.y + ak.z*ak.z + ak.w*ak.w), 1e-12f);
        float nv = 1.0f / fmaxf(sqrtf(av.x*av.x + av.y*av.y + av.z*av.z + av.w*av.w), 1e-12f);
        aq.x *= nq; aq.y *= nq; aq.z *= nq; aq.w *= nq;
        ak.x *= nk; ak.y *= nk; ak.z *= nk; ak.w *= nk;
        av.x *= nv; av.y *= nv; av.z *= nv; av.w *= nv;
        *(float4*)&qsf[l * 36 + 4 * q] = aq;
        *(float4*)&ksf[l * 36 + 4 * q] = ak;
        *(float4*)&vsf[l * 36 + 4 * q] = av;
    }
    __syncthreads();

    // ---- stage wm (linear b128 from pre-transposed ws) + raw logits (bf16) ----
    {
        float4 v = ((const float4*)(ws + 4608))[tid];   // 256 float4 = whole m_w^T
        *(float4*)&wmf[tid * 4] = v;
    }
    if (tid < 192) {                    // thread = (h, i2): one raw-logit row -> bf16
        int h = tid & 7, i2 = tid >> 3;
        float4 q4 = *(const float4*)&qsf[i2 * 36 + 4 * h];
        float row[24];
        #pragma unroll
        for (int j = 0; j < 24; j++) {
            float4 k4 = *(const float4*)&ksf[j * 36 + 4 * h];
            row[j] = q4.x * k4.x + q4.y * k4.y + q4.z * k4.z + q4.w * k4.w;
        }
        #pragma unroll
        for (int j = 0; j < 24; j++) lgh[i2 * 200 + j * 8 + h] = __float2bfloat16(row[j]);
    }
    __syncthreads();

    // ---- fused W_logit mix + rel-pos bias + softmax (registers) ----
    // thread = (H = tid&7, i = tid>>3); reads all 8 h as ONE b128 (4 u32 bf16-pairs)
    float sm[24];
    {
        if (tid < 192) {
            int H = tid & 7, i = tid >> 3;
            float wlc[8];
            #pragma unroll
            for (int h = 0; h < 8; h++) wlc[h] = wl05f[h * 8 + H];
            float mx = -1e30f;
            #pragma unroll
            for (int j = 0; j < 24; j++) {
                uint4 ua = *(const uint4*)&lgu[i * 100 + j * 4];
                float t0,t1,t2,t3,t4,t5,t6,t7;
                bf2(ua.x, t0, t1); bf2(ua.y, t2, t3);
                bf2(ua.z, t4, t5); bf2(ua.w, t6, t7);
                float a = rpmf[H * 48 + (i - j + 23)];
                a += t0 * wlc[0] + t1 * wlc[1] + t2 * wlc[2] + t3 * wlc[3]
                   + t4 * wlc[4] + t5 * wlc[5] + t6 * wlc[6] + t7 * wlc[7];
                sm[j] = a;
                mx = fmaxf(mx, a);
            }
            float s = 0.0f;
            #pragma unroll
            for (int j = 0; j < 24; j++) { float e = __expf(sm[j] - mx); sm[j] = e; s += e; }
            float inv = 1.0f / s;
            #pragma unroll
            for (int j = 0; j < 24; j++) sm[j] *= inv;
        }
        __syncthreads();                 // all reads of raw logits done before overwrite
        if (tid < 192) {
            int H = tid & 7, i = tid >> 3;
            #pragma unroll
            for (int j = 0; j < 24; j++) lgh[i * 200 + j * 8 + H] = __float2bfloat16(sm[j]);
        }
    }
    __syncthreads();

    // ---- fused W_ctx mix + PV: thread = (l, head q); ONE b128 per j ----
    if (tid < 192) {
        int l = tid >> 3, q = tid & 7;
        float wcc[8];
        #pragma unroll
        for (int h = 0; h < 8; h++) wcc[h] = wcf[h * 8 + q];
        float4 acc = {0.0f, 0.0f, 0.0f, 0.0f};
        #pragma unroll
        for (int j = 0; j < 24; j++) {
            uint4 ua = *(const uint4*)&lgu[l * 100 + j * 4];
            float t0,t1,t2,t3,t4,t5,t6,t7;
            bf2(ua.x, t0, t1); bf2(ua.y, t2, t3);
            bf2(ua.z, t4, t5); bf2(ua.w, t6, t7);
            float a = t0 * wcc[0] + t1 * wcc[1] + t2 * wcc[2] + t3 * wcc[3]
                    + t4 * wcc[4] + t5 * wcc[5] + t6 * wcc[6] + t7 * wcc[7];
            float4 v4 = *(const float4*)&vsf[j * 36 + 4 * q];
            acc.x += a * v4.x; acc.y += a * v4.y; acc.z += a * v4.z; acc.w += a * v4.w;
        }
        *(float4*)&fusedf[l * 36 + 4 * q] = acc;
    }
    __syncthreads();

    // ---- m_w projection -> res[c][l] (stride 25, reuses qs region) ----
    if (tid < 192) {
        int l = tid >> 3, q = tid & 7;
        float4 acc = *(const float4*)&bmf[4 * q];
        #pragma unroll
        for (int cq = 0; cq < 8; cq++) {
            float4 f4 = *(const float4*)&fusedf[l * 36 + 4 * cq];
            float fv[4] = {f4.x, f4.y, f4.z, f4.w};
            #pragma unroll
            for (int cc = 0; cc < 4; cc++) {
                int c = 4 * cq + cc;
                int sw = (4 * q) ^ (c & 28);
                float f = fv[cc];
                float4 w4 = *(const float4*)&wmf[c * 32 + sw];
                acc.x += f * w4.x; acc.y += f * w4.y; acc.z += f * w4.z; acc.w += f * w4.w;
            }
        }
        float* resf = qsf;
        resf[(4 * q + 0) * 25 + l] = acc.x;
        resf[(4 * q + 1) * 25 + l] = acc.y;
        resf[(4 * q + 2) * 25 + l] = acc.z;
        resf[(4 * q + 3) * 25 + l] = acc.w;
    }
    __syncthreads();

    // ---- coalesced global write ----
    if (tid < 192) {
        const float* resf = qsf;
        int c = tid / 6, k = tid - c * 6;
        float4 v;
        v.x = resf[c * 25 + 4 * k + 0];
        v.y = resf[c * 25 + 4 * k + 1];
        v.z = resf[c * 25 + 4 * k + 2];
        v.w = resf[c * 25 + 4 * k + 3];
        float4* o4 = (float4*)(out + (size_t)b * (DD * NPOS) + (size_t)c * NPOS + t * LL);
        o4[k] = v;
    }
}

// ---------------- K3: prediction branch (256 threads) ----------------
__global__ __launch_bounds__(256) void k3_pred(
    const float* __restrict__ pre_prompt,
    const float* __restrict__ conv_w, const float* __restrict__ conv_b,
    const float* __restrict__ p_w, const float* __restrict__ p_b,
    float* __restrict__ out)
{
    __shared__ float conf[DD * NPOS];            // 6912 floats
    __shared__ __hip_bfloat16 cwh[DD * 324];     // [co][ci*10+tt], per-co stride 324 (320 used)
    __shared__ float pbuff[DD * 25];             // [co][l] stride 25
    __shared__ __hip_bfloat16 pwh[24 * 28];      // [l_out][l_in], row stride 28 (24 used)
    __shared__ float pbv[24], cbv[32];
    int b = blockIdx.x, tid = threadIdx.x;

    const float4* o4 = (const float4*)(out + (size_t)b * (DD * NPOS));
    for (int idx = tid; idx < 1728; idx += 256) {
        int flat = idx * 4;
        int t = (flat % NPOS) / LL;              // uniform within the float4
        float4 v;
        if (t < 8) {
            v = o4[idx];
        } else {
            int c = flat / NPOS, l = flat % LL;  // 192 % 24 == 0
            v = ((const float4*)pre_prompt)[(c * LL + l) >> 2];
        }
        *(float4*)&conf[flat] = v;               // contiguous b128 store: conflict-free
    }
    for (int idx = tid; idx < 2304; idx += 256) {
        float4 v = ((const float4*)conv_w)[idx];
        int flat = idx * 4;
        float vv[4] = {v.x, v.y, v.z, v.w};
        #pragma unroll
        for (int e = 0; e < 4; e++) {
            int f = flat + e;
            int co = f / 288, r = f - co * 288;
            int ci = r / 9, ttt = r - ci * 9;
            cwh[co * 324 + ci * 10 + ttt] = __float2bfloat16(vv[e]);
        }
    }
    for (int idx = tid; idx < 144; idx += 256) {
        float4 v = ((const float4*)p_w)[idx];
        int flat = idx * 4;
        float vv[4] = {v.x, v.y, v.z, v.w};
        #pragma unroll
        for (int e = 0; e < 4; e++) {
            int f = flat + e;
            int row = f / 24, col = f - row * 24;
            pwh[row * 28 + col] = __float2bfloat16(vv[e]);
        }
    }
    if (tid < 24) pbv[tid] = p_b[tid];
    if (tid >= 32 && tid < 64) cbv[tid - 32] = conv_b[tid - 32];
    __syncthreads();

    // conv over contexts: thread = (co, l-quad)
    if (tid < 192) {
        int co = tid / 6, ql = tid - co * 6;
        float cb = cbv[co];
        float4 acc = {cb, cb, cb, cb};
        const float4* cf4 = (const float4*)conf;    // [ci][tt][ql] -> ci*54 + tt*6 + ql
        for (int ci = 0; ci < 32; ci++) {
            const uint32_t* wp = (const uint32_t*)&cwh[co * 324 + ci * 10];
            #pragma unroll
            for (int p = 0; p < 4; p++) {
                uint32_t u = wp[p];
                float w0 = __uint_as_float(u << 16);
                float w1 = __uint_as_float(u & 0xffff0000u);
                float4 v0 = cf4[ci * 54 + (2 * p) * 6 + ql];
                float4 v1 = cf4[ci * 54 + (2 * p + 1) * 6 + ql];
                acc.x += w0 * v0.x + w1 * v1.x;
                acc.y += w0 * v0.y + w1 * v1.y;
                acc.z += w0 * v0.z + w1 * v1.z;
                acc.w += w0 * v0.w + w1 * v1.w;
            }
            float w8 = __bfloat162float(cwh[co * 324 + ci * 10 + 8]);
            float4 v8 = cf4[ci * 54 + 48 + ql];
            acc.x += w8 * v8.x; acc.y += w8 * v8.y; acc.z += w8 * v8.z; acc.w += w8 * v8.w;
        }
        pbuff[co * 25 + 4 * ql + 0] = fmaxf(acc.x, 0.0f);
        pbuff[co * 25 + 4 * ql + 1] = fmaxf(acc.y, 0.0f);
        pbuff[co * 25 + 4 * ql + 2] = fmaxf(acc.z, 0.0f);
        pbuff[co * 25 + 4 * ql + 3] = fmaxf(acc.w, 0.0f);
    }
    __syncthreads();

    // token linear + subtraction into the t=8 plane
    if (tid < 192) {
        int c = tid / 6, ql = tid - c * 6;
        float accv[4] = {pbv[4 * ql + 0], pbv[4 * ql + 1], pbv[4 * ql + 2], pbv[4 * ql + 3]};
        #pragma unroll
        for (int lp = 0; lp < 24; lp += 2) {
            float pv0 = pbuff[c * 25 + lp];
            float pv1 = pbuff[c * 25 + lp + 1];
            #pragma unroll
            for (int e = 0; e < 4; e++) {
                uint32_t u = *(const uint32_t*)&pwh[(4 * ql + e) * 28 + lp];
                accv[e] += pv0 * __uint_as_float(u << 16) + pv1 * __uint_as_float(u & 0xffff0000u);
            }
        }
        float4* op = (float4*)(out + (size_t)b * (DD * NPOS) + (size_t)c * NPOS + 8 * LL);
        float4 xa = op[ql];
        float4 r;
        r.x = xa.x - accv[0]; r.y = xa.y - accv[1]; r.z = xa.z - accv[2]; r.w = xa.w - accv[3];
        op[ql] = r;
    }
}

extern "C" void kernel_launch(void* const* d_in, const int* in_sizes, int n_in,
                              void* d_out, int out_size, void* d_ws, size_t ws_size,
                              hipStream_t stream) {
    const float* x        = (const float*)d_in[0];
    const float* ln_g     = (const float*)d_in[1];
    const float* ln_b     = (const float*)d_in[2];
    const float* rp_w1    = (const float*)d_in[3];
    const float* rp_b1    = (const float*)d_in[4];
    const float* rp_w2    = (const float*)d_in[5];
    const float* rp_b2    = (const float*)d_in[6];
    const float* W_causal = (const float*)d_in[7];
    const float* mask_w   = (const float*)d_in[8];
    const float* mask_b   = (const float*)d_in[9];
    const float* val_w1   = (const float*)d_in[10];
    const float* val_b1   = (const float*)d_in[11];
    const float* val_w2   = (const float*)d_in[12];
    const float* val_b2   = (const float*)d_in[13];
    const float* fuse_g   = (const float*)d_in[14];
    const float* q_w      = (const float*)d_in[15];
    const float* q_b      = (const float*)d_in[16];
    const float* k_w      = (const float*)d_in[17];
    const float* k_b      = (const float*)d_in[18];
    const float* v_w      = (const float*)d_in[19];
    const float* v_b      = (const float*)d_in[20];
    const float* m_w      = (const float*)d_in[21];
    const float* m_b      = (const float*)d_in[22];
    const float* W_logit  = (const float*)d_in[23];
    const float* W_ctx    = (const float*)d_in[24];
    const float* rel_pb   = (const float*)d_in[25];
    const float* pre_pr   = (const float*)d_in[26];
    const float* conv_w   = (const float*)d_in[27];
    const float* conv_b   = (const float*)d_in[28];
    const float* p_w      = (const float*)d_in[29];
    const float* p_b      = (const float*)d_in[30];
    float* out = (float*)d_out;

    int B = in_sizes[0] / (DD * NPOS);

    float* ws = (float*)d_ws;
    float* sp = ws + 8192;            // B*32 sums, then overwritten with g*delta
    float* sq = sp + (size_t)B * 32;  // B*32 sum-of-squares

    hipLaunchKernelGGL(k0_prep, dim3(1), dim3(1024), 0, stream,
                       W_causal, W_logit, rel_pb, q_w, k_w, v_w, m_w, ws);
    hipLaunchKernelGGL(k1a, dim3(B), dim3(256), 0, stream, x, sp, sq);
    hipLaunchKernelGGL(k1b, dim3(B / 64), dim3(64), 0, stream,
                       ln_g, ln_b, rp_w1, rp_b1, rp_w2, rp_b2,
                       mask_w, mask_b, val_w1, val_b1, val_w2, val_b2,
                       fuse_g, ws, sp, sq);
    hipLaunchKernelGGL(k2_attn, dim3(B * TT), dim3(256), 0, stream,
                       x, ws, sp, q_b, k_b, v_b, m_b, W_ctx, out);
    hipLaunchKernelGGL(k3_pred, dim3(B), dim3(256), 0, stream,
                       pre_pr, conv_w, conv_b, p_w, p_b, out);
}

// Round 7
// 972.482 us; speedup vs baseline: 2.0371x; 1.0521x over previous
//
#include <hip/hip_runtime.h>
#include <hip/hip_bf16.h>

#define DD 32
#define TT 9
#define LL 24
#define HH 8
#define NPOS 216           // TT*LL
#define RPB_W 47           // 2*LL-1
#define ALPHA 0.9f

__device__ __forceinline__ float gelu_exact(float x) {
    return 0.5f * x * (1.0f + erff(x * 0.7071067811865476f));
}
__device__ __forceinline__ float sigmoidf_(float x) { return 1.0f / (1.0f + expf(-x)); }

// ws float layout: [0,1024) a32 ; [1024,1088) wl05 ; [1088,1480) rpm[8][49] ;
// [1536,2560) q_w^T swz ; [2560,3584) k_w^T swz ; [3584,4608) v_w^T swz ;
// [4608,5632) m_w^T swz ; [8192, 8192+B*32) spool/delta ; then ssq (B*32)

// ---------------- K0: a32 + premixed W_logit/rel-pos + pre-transposed weights ----------------
__global__ void k0_prep(const float* __restrict__ wcausal,
                        const float* __restrict__ w_logit,
                        const float* __restrict__ rpb,
                        const float* __restrict__ q_w, const float* __restrict__ k_w,
                        const float* __restrict__ v_w, const float* __restrict__ m_w,
                        float* __restrict__ ws) {
    __shared__ float A[DD][DD];
    __shared__ float rs[DD];
    int tid = threadIdx.x;              // 1024 threads
    int i = tid >> 5, j = tid & 31;
    float a = (i == j) ? 0.0f : log1pf(expf(wcausal[tid]));
    A[i][j] = a;
    __syncthreads();
    if (j == 0) {
        float s = 0.0f;
        for (int k = 0; k < DD; k++) s += A[i][k];
        rs[i] = ALPHA / (s + 1e-6f);
    }
    __syncthreads();
    ws[tid] = A[i][j] * rs[i];
    if (tid < 64) ws[1024 + tid] = 0.5f * w_logit[tid];
    if (tid < 392) {                    // rpm[8][49] (stride 49 for bank spread)
        int H = tid / 49, r = tid % 49;
        float v = 0.0f;
        if (r < RPB_W) {
            for (int h = 0; h < HH; h++) v += w_logit[h * HH + H] * rpb[h * RPB_W + r];
        }
        ws[1088 + tid] = v;
    }
    // pre-transpose + XOR-swizzle: dst[j*32 + (i ^ (j&28))] = w[i*32 + j]
    {
        int dsti = j * 32 + (i ^ (j & 28));
        ws[1536 + dsti] = q_w[tid];
        ws[2560 + dsti] = k_w[tid];
        ws[3584 + dsti] = v_w[tid];
        ws[4608 + dsti] = m_w[tid];
    }
}

// ---------------- K1a: per-(b,c) sum / sum-of-squares (memory-bound) ----------------
__global__ __launch_bounds__(256) void k1a(const float* __restrict__ x,
                                           float* __restrict__ sp, float* __restrict__ sq) {
    int b = blockIdx.x, tid = threadIdx.x;
    int c = tid >> 3, r = tid & 7;
    const float4* x4 = (const float4*)(x + (size_t)b * (DD * NPOS) + (size_t)c * NPOS);
    float s = 0.0f, q = 0.0f;
    for (int k = r; k < 54; k += 8) {   // 54 float4 = 216 floats
        float4 v = x4[k];
        s += v.x + v.y + v.z + v.w;
        q += v.x * v.x + v.y * v.y + v.z * v.z + v.w * v.w;
    }
    for (int m = 1; m < 8; m <<= 1) { s += __shfl_xor(s, m); q += __shfl_xor(q, m); }
    if (r == 0) { sp[b * DD + c] = s; sq[b * DD + c] = q; }
}

// ---------------- K1b: one batch element per thread; full chain in registers ----------------
__global__ __launch_bounds__(64) void k1b(
    const float* __restrict__ ln_g, const float* __restrict__ ln_b,
    const float* __restrict__ rp_w1, const float* __restrict__ rp_b1,
    const float* __restrict__ rp_w2, const float* __restrict__ rp_b2,
    const float* __restrict__ mask_w, const float* __restrict__ mask_b,
    const float* __restrict__ val_w1, const float* __restrict__ val_b1,
    const float* __restrict__ val_w2, const float* __restrict__ val_b2,
    const float* __restrict__ fuse_gate, const float* __restrict__ ws,
    float* __restrict__ sp /* in: sums; out: g*delta */, const float* __restrict__ sq)
{
    __shared__ float W[6][1024];   // rp_w1, rp_w2, mask_w, val_w1, val_w2, a32
    __shared__ float V[7][32];     // ln_g, ln_b, rp_b1, rp_b2, mask_b, val_b1, val_b2
    int tid = threadIdx.x;
    for (int idx = tid; idx < 1024; idx += 64) {
        W[0][idx] = rp_w1[idx]; W[1][idx] = rp_w2[idx]; W[2][idx] = mask_w[idx];
        W[3][idx] = val_w1[idx]; W[4][idx] = val_w2[idx]; W[5][idx] = ws[idx];
    }
    if (tid < 32) {
        V[0][tid] = ln_g[tid]; V[1][tid] = ln_b[tid]; V[2][tid] = rp_b1[tid];
        V[3][tid] = rp_b2[tid]; V[4][tid] = mask_b[tid]; V[5][tid] = val_b1[tid];
        V[6][tid] = val_b2[tid];
    }
    __syncthreads();
    int b = blockIdx.x * 64 + tid;

    float pooled[32], scl[32];
    const float4* sp4 = (const float4*)(sp + (size_t)b * 32);
    const float4* sq4 = (const float4*)(sq + (size_t)b * 32);
    #pragma unroll
    for (int k = 0; k < 8; k++) {
        float4 sv = sp4[k], qv = sq4[k];
        float ss[4] = {sv.x, sv.y, sv.z, sv.w};
        float qq[4] = {qv.x, qv.y, qv.z, qv.w};
        #pragma unroll
        for (int m = 0; m < 4; m++) {
            int c = 4 * k + m;
            float p = ss[m] * (1.0f / NPOS);
            pooled[c] = p;
            float var1 = (qq[m] - (float)NPOS * p * p) * (1.0f / (NPOS - 1));
            scl[c] = fmaxf(sqrtf(fmaxf(var1, 0.0f)), 1e-3f);
        }
    }
    float mu = 0.0f;
    #pragma unroll
    for (int c = 0; c < 32; c++) mu += pooled[c];
    mu *= (1.0f / 32.0f);
    float vv = 0.0f;
    #pragma unroll
    for (int c = 0; c < 32; c++) { float d = pooled[c] - mu; vv += d * d; }
    vv *= (1.0f / 32.0f);
    float inv = rsqrtf(vv + 1e-5f);
    float pn[32];
    #pragma unroll
    for (int c = 0; c < 32; c++) pn[c] = (pooled[c] - mu) * inv * V[0][c] + V[1][c];

    float h1[32];
    #pragma unroll
    for (int i = 0; i < 32; i++) {
        float acc = V[2][i];
        #pragma unroll
        for (int j = 0; j < 32; j++) acc += pn[j] * W[0][i * 32 + j];
        h1[i] = gelu_exact(acc);
    }
    float pr[32];
    #pragma unroll
    for (int i = 0; i < 32; i++) {
        float acc = V[3][i];
        #pragma unroll
        for (int j = 0; j < 32; j++) acc += h1[j] * W[1][i * 32 + j];
        pr[i] = acc;
    }
    float g1[32];
    #pragma unroll
    for (int i = 0; i < 32; i++) {
        float acc = V[5][i];
        #pragma unroll
        for (int j = 0; j < 32; j++) acc += pr[j] * W[3][i * 32 + j];
        g1[i] = gelu_exact(acc);
    }
    float xd[32];
    #pragma unroll
    for (int i = 0; i < 32; i++) {
        float am = V[4][i];
        #pragma unroll
        for (int j = 0; j < 32; j++) am += pr[j] * W[2][i * 32 + j];
        float M = sigmoidf_(am);
        float av = V[6][i];
        #pragma unroll
        for (int j = 0; j < 32; j++) av += g1[j] * W[4][i * 32 + j];
        float v32 = tanhf(av) * scl[i] + pooled[i];
        xd[i] = (1.0f - M) * pooled[i] + M * v32;
    }
    float y[32];
    #pragma unroll
    for (int c = 0; c < 32; c++) y[c] = xd[c];
    for (int it = 0; it < 3; it++) {
        float ny[32];
        #pragma unroll
        for (int i = 0; i < 32; i++) {
            float acc = xd[i];
            #pragma unroll
            for (int j = 0; j < 32; j++) acc += y[j] * W[5][i * 32 + j];
            ny[i] = acc;
        }
        #pragma unroll
        for (int c = 0; c < 32; c++) y[c] = ny[c];
    }
    float g = sigmoidf_(fuse_gate[0]);
    float4* dout4 = (float4*)(sp + (size_t)b * 32);
    #pragma unroll
    for (int k = 0; k < 8; k++) {
        float4 o;
        o.x = g * (y[4 * k + 0] - pooled[4 * k + 0]);
        o.y = g * (y[4 * k + 1] - pooled[4 * k + 1]);
        o.z = g * (y[4 * k + 2] - pooled[4 * k + 2]);
        o.w = g * (y[4 * k + 3] - pooled[4 * k + 3]);
        dout4[k] = o;
    }
}

// ---------------- K2: per (b,t) attention ----------------
// VALU+LDS joint-envelope kernel. r3 structure (fp32 lg2, stride 196) + r6's
// pre-transposed weight staging (linear b128 copies) + no-max softmax (logits
// bounded by cosine-sim construction: |mixed logit| <= ~0.6) + rpm stride 49.
// r1 = fused/qs/ks/vs [24][36]. r2: phase A wq|wk|wv swz (3072);
// phase C+ lg2[i][j][h] stride 196 (4700), wm swz at 4800.
__global__ __launch_bounds__(256) void k2_attn(
    const float* __restrict__ x,
    const float* __restrict__ ws,        // wl05 @1024, rpm @1088, weights @1536
    const float* __restrict__ delta,
    const float* __restrict__ q_b, const float* __restrict__ k_b,
    const float* __restrict__ v_b, const float* __restrict__ m_b,
    const float* __restrict__ w_ctx,
    float* __restrict__ out)
{
    __shared__ float r1[3456];
    __shared__ float r2[5824];
    __shared__ float msc[656];
    float* fusedf = r1;                 // [24][36]
    float* qsf = r1 + 864;
    float* ksf = r1 + 1728;
    float* vsf = r1 + 2592;
    float* wqf = r2;                    // phase A: swizzled transposed [32][32]
    float* wkf = r2 + 1024;
    float* wvf = r2 + 2048;
    float* lg2 = r2;                    // phase C+: [i][j][h], per-i stride 196
    float* wmf = r2 + 4800;             // swizzled transposed [32][32]
    float* bqf = msc, *bkf = msc + 32, *bvf = msc + 64, *bmf = msc + 96;
    float* wl05f = msc + 128;
    float* wcf = msc + 192;
    float* rpmf = msc + 256;            // [8][49]

    int blk = blockIdx.x;
    int b = blk / TT, t = blk % TT;
    int tid = threadIdx.x;

    // ---- stage (weights already transposed+swizzled in ws: linear b128 copy) ----
    for (int idx = tid; idx < 768; idx += 256) {
        float4 v = ((const float4*)(ws + 1536))[idx];
        *(float4*)&r2[idx * 4] = v;
    }
    if (tid < 32) { bqf[tid] = q_b[tid]; bkf[tid] = k_b[tid]; bvf[tid] = v_b[tid]; bmf[tid] = m_b[tid]; }
    else if (tid < 96) wl05f[tid - 32] = ws[1024 + tid - 32];
    else if (tid < 160) wcf[tid - 96] = w_ctx[tid - 96];
    for (int idx = tid; idx < 392; idx += 256) rpmf[idx] = ws[1088 + idx];
    if (tid < 192) {                    // fused[l][c] = x + delta
        int c = tid / 6, k = tid % 6;
        const float4* p = (const float4*)(x + (size_t)b * (DD * NPOS) + (size_t)c * NPOS + t * LL);
        float4 v = p[k];
        float gd = delta[b * DD + c];
        int l0 = 4 * k;
        fusedf[(l0 + 0) * 36 + c] = v.x + gd;
        fusedf[(l0 + 1) * 36 + c] = v.y + gd;
        fusedf[(l0 + 2) * 36 + c] = v.z + gd;
        fusedf[(l0 + 3) * 36 + c] = v.w + gd;
    }
    __syncthreads();

    // ---- q/k/v projection: thread = (l, head q); f rows read as b128 ----
    if (tid < 192) {
        int l = tid >> 3, q = tid & 7;
        float4 aq = *(const float4*)&bqf[4 * q];
        float4 ak = *(const float4*)&bkf[4 * q];
        float4 av = *(const float4*)&bvf[4 * q];
        #pragma unroll
        for (int jq = 0; jq < 8; jq++) {
            float4 f4 = *(const float4*)&fusedf[l * 36 + 4 * jq];
            float fv[4] = {f4.x, f4.y, f4.z, f4.w};
            #pragma unroll
            for (int jj = 0; jj < 4; jj++) {
                int j = 4 * jq + jj;
                int sw = (4 * q) ^ (j & 28);
                float f = fv[jj];
                float4 w0 = *(const float4*)&wqf[j * 32 + sw];
                float4 w1 = *(const float4*)&wkf[j * 32 + sw];
                float4 w2 = *(const float4*)&wvf[j * 32 + sw];
                aq.x += f * w0.x; aq.y += f * w0.y; aq.z += f * w0.z; aq.w += f * w0.w;
                ak.x += f * w1.x; ak.y += f * w1.y; ak.z += f * w1.z; ak.w += f * w1.w;
                av.x += f * w2.x; av.y += f * w2.y; av.z += f * w2.z; av.w += f * w2.w;
            }
        }
        float nq = 1.0f / fmaxf(sqrtf(aq.x*aq.x + aq.y*aq.y + aq.z*aq.z + aq.w*aq.w), 1e-12f);
        float nk = 1.0f / fmaxf(sqrtf(ak.x*ak.x + ak.y*ak.y + ak.z*ak.z + ak.w*ak.w), 1e-12f);
        float nv = 1.0f / fmaxf(sqrtf(av.x*av.x + av.y*av.y + av.z*av.z + av.w*av.w), 1e-12f);
        aq.x *= nq; aq.y *= nq; aq.z *= nq; aq.w *= nq;
        ak.x *= nk; ak.y *= nk; ak.z *= nk; ak.w *= nk;
        av.x *= nv; av.y *= nv; av.z *= nv; av.w *= nv;
        *(float4*)&qsf[l * 36 + 4 * q] = aq;
        *(float4*)&ksf[l * 36 + 4 * q] = ak;
        *(float4*)&vsf[l * 36 + 4 * q] = av;
    }
    __syncthreads();

    // ---- stage wm (linear b128 from pre-transposed ws) + raw logits ----
    {
        float4 v = ((const float4*)(ws + 4608))[tid];   // 256 float4 = whole m_w^T
        *(float4*)&wmf[tid * 4] = v;
    }
    if (tid < 192) {                    // thread = (h, i2): one raw-logit row
        int h = tid & 7, i2 = tid >> 3;
        float4 q4 = *(const float4*)&qsf[i2 * 36 + 4 * h];
        float row[24];
        #pragma unroll
        for (int j = 0; j < 24; j++) {
            float4 k4 = *(const float4*)&ksf[j * 36 + 4 * h];
            row[j] = q4.x * k4.x + q4.y * k4.y + q4.z * k4.z + q4.w * k4.w;
        }
        #pragma unroll
        for (int j = 0; j < 24; j++) lg2[i2 * 196 + j * 8 + h] = row[j];
    }
    __syncthreads();

    // ---- fused W_logit mix + rel-pos bias + softmax (registers, NO max-sub) ----
    // logits bounded: q,k unit-norm per head -> |0.5*qk| <= 0.5; |mix| <= ~0.6.
    float sm[24];
    {
        if (tid < 192) {
            int H = tid & 7, i = tid >> 3;
            float wlc[8];
            #pragma unroll
            for (int h = 0; h < 8; h++) wlc[h] = wl05f[h * 8 + H];
            float s = 0.0f;
            #pragma unroll
            for (int j = 0; j < 24; j++) {
                float4 ta = *(const float4*)&lg2[i * 196 + j * 8];
                float4 tb = *(const float4*)&lg2[i * 196 + j * 8 + 4];
                float a = rpmf[H * 49 + (i - j + 23)];
                a += ta.x * wlc[0] + ta.y * wlc[1] + ta.z * wlc[2] + ta.w * wlc[3]
                   + tb.x * wlc[4] + tb.y * wlc[5] + tb.z * wlc[6] + tb.w * wlc[7];
                float e = __expf(a);
                sm[j] = e;
                s += e;
            }
            float inv = 1.0f / s;
            #pragma unroll
            for (int j = 0; j < 24; j++) sm[j] *= inv;
        }
        __syncthreads();                 // all reads of raw logits done before overwrite
        if (tid < 192) {
            int H = tid & 7, i = tid >> 3;
            #pragma unroll
            for (int j = 0; j < 24; j++) lg2[i * 196 + j * 8 + H] = sm[j];
        }
    }
    __syncthreads();

    // ---- fused W_ctx mix + PV: thread = (l, head q); x_att into fused region ----
    if (tid < 192) {
        int l = tid >> 3, q = tid & 7;
        float wcc[8];
        #pragma unroll
        for (int h = 0; h < 8; h++) wcc[h] = wcf[h * 8 + q];
        float4 acc = {0.0f, 0.0f, 0.0f, 0.0f};
        #pragma unroll
        for (int j = 0; j < 24; j++) {
            float4 ta = *(const float4*)&lg2[l * 196 + j * 8];
            float4 tb = *(const float4*)&lg2[l * 196 + j * 8 + 4];
            float a = ta.x * wcc[0] + ta.y * wcc[1] + ta.z * wcc[2] + ta.w * wcc[3]
                    + tb.x * wcc[4] + tb.y * wcc[5] + tb.z * wcc[6] + tb.w * wcc[7];
            float4 v4 = *(const float4*)&vsf[j * 36 + 4 * q];
            acc.x += a * v4.x; acc.y += a * v4.y; acc.z += a * v4.z; acc.w += a * v4.w;
        }
        *(float4*)&fusedf[l * 36 + 4 * q] = acc;
    }
    __syncthreads();

    // ---- m_w projection -> res[c][l] (stride 25, reuses qs region) ----
    if (tid < 192) {
        int l = tid >> 3, q = tid & 7;
        float4 acc = *(const float4*)&bmf[4 * q];
        #pragma unroll
        for (int cq = 0; cq < 8; cq++) {
            float4 f4 = *(const float4*)&fusedf[l * 36 + 4 * cq];
            float fv[4] = {f4.x, f4.y, f4.z, f4.w};
            #pragma unroll
            for (int cc = 0; cc < 4; cc++) {
                int c = 4 * cq + cc;
                int sw = (4 * q) ^ (c & 28);
                float f = fv[cc];
                float4 w4 = *(const float4*)&wmf[c * 32 + sw];
                acc.x += f * w4.x; acc.y += f * w4.y; acc.z += f * w4.z; acc.w += f * w4.w;
            }
        }
        float* resf = qsf;
        resf[(4 * q + 0) * 25 + l] = acc.x;
        resf[(4 * q + 1) * 25 + l] = acc.y;
        resf[(4 * q + 2) * 25 + l] = acc.z;
        resf[(4 * q + 3) * 25 + l] = acc.w;
    }
    __syncthreads();

    // ---- coalesced global write ----
    if (tid < 192) {
        const float* resf = qsf;
        int c = tid / 6, k = tid - c * 6;
        float4 v;
        v.x = resf[c * 25 + 4 * k + 0];
        v.y = resf[c * 25 + 4 * k + 1];
        v.z = resf[c * 25 + 4 * k + 2];
        v.w = resf[c * 25 + 4 * k + 3];
        float4* o4 = (float4*)(out + (size_t)b * (DD * NPOS) + (size_t)c * NPOS + t * LL);
        o4[k] = v;
    }
}

// ---------------- K3: prediction branch (256 threads) ----------------
__global__ __launch_bounds__(256) void k3_pred(
    const float* __restrict__ pre_prompt,
    const float* __restrict__ conv_w, const float* __restrict__ conv_b,
    const float* __restrict__ p_w, const float* __restrict__ p_b,
    float* __restrict__ out)
{
    __shared__ float conf[DD * NPOS];            // 6912 floats
    __shared__ __hip_bfloat16 cwh[DD * 324];     // [co][ci*10+tt], per-co stride 324 (320 used)
    __shared__ float pbuff[DD * 25];             // [co][l] stride 25
    __shared__ __hip_bfloat16 pwh[24 * 28];      // [l_out][l_in], row stride 28 (24 used)
    __shared__ float pbv[24], cbv[32];
    int b = blockIdx.x, tid = threadIdx.x;

    const float4* o4 = (const float4*)(out + (size_t)b * (DD * NPOS));
    for (int idx = tid; idx < 1728; idx += 256) {
        int flat = idx * 4;
        int t = (flat % NPOS) / LL;              // uniform within the float4
        float4 v;
        if (t < 8) {
            v = o4[idx];
        } else {
            int c = flat / NPOS, l = flat % LL;  // 192 % 24 == 0
            v = ((const float4*)pre_prompt)[(c * LL + l) >> 2];
        }
        *(float4*)&conf[flat] = v;               // contiguous b128 store: conflict-free
    }
    for (int idx = tid; idx < 2304; idx += 256) {
        float4 v = ((const float4*)conv_w)[idx];
        int flat = idx * 4;
        float vv[4] = {v.x, v.y, v.z, v.w};
        #pragma unroll
        for (int e = 0; e < 4; e++) {
            int f = flat + e;
            int co = f / 288, r = f - co * 288;
            int ci = r / 9, ttt = r - ci * 9;
            cwh[co * 324 + ci * 10 + ttt] = __float2bfloat16(vv[e]);
        }
    }
    for (int idx = tid; idx < 144; idx += 256) {
        float4 v = ((const float4*)p_w)[idx];
        int flat = idx * 4;
        float vv[4] = {v.x, v.y, v.z, v.w};
        #pragma unroll
        for (int e = 0; e < 4; e++) {
            int f = flat + e;
            int row = f / 24, col = f - row * 24;
            pwh[row * 28 + col] = __float2bfloat16(vv[e]);
        }
    }
    if (tid < 24) pbv[tid] = p_b[tid];
    if (tid >= 32 && tid < 64) cbv[tid - 32] = conv_b[tid - 32];
    __syncthreads();

    // conv over contexts: thread = (co, l-quad)
    if (tid < 192) {
        int co = tid / 6, ql = tid - co * 6;
        float cb = cbv[co];
        float4 acc = {cb, cb, cb, cb};
        const float4* cf4 = (const float4*)conf;    // [ci][tt][ql] -> ci*54 + tt*6 + ql
        for (int ci = 0; ci < 32; ci++) {
            const uint32_t* wp = (const uint32_t*)&cwh[co * 324 + ci * 10];
            #pragma unroll
            for (int p = 0; p < 4; p++) {
                uint32_t u = wp[p];
                float w0 = __uint_as_float(u << 16);
                float w1 = __uint_as_float(u & 0xffff0000u);
                float4 v0 = cf4[ci * 54 + (2 * p) * 6 + ql];
                float4 v1 = cf4[ci * 54 + (2 * p + 1) * 6 + ql];
                acc.x += w0 * v0.x + w1 * v1.x;
                acc.y += w0 * v0.y + w1 * v1.y;
                acc.z += w0 * v0.z + w1 * v1.z;
                acc.w += w0 * v0.w + w1 * v1.w;
            }
            float w8 = __bfloat162float(cwh[co * 324 + ci * 10 + 8]);
            float4 v8 = cf4[ci * 54 + 48 + ql];
            acc.x += w8 * v8.x; acc.y += w8 * v8.y; acc.z += w8 * v8.z; acc.w += w8 * v8.w;
        }
        pbuff[co * 25 + 4 * ql + 0] = fmaxf(acc.x, 0.0f);
        pbuff[co * 25 + 4 * ql + 1] = fmaxf(acc.y, 0.0f);
        pbuff[co * 25 + 4 * ql + 2] = fmaxf(acc.z, 0.0f);
        pbuff[co * 25 + 4 * ql + 3] = fmaxf(acc.w, 0.0f);
    }
    __syncthreads();

    // token linear + subtraction into the t=8 plane
    if (tid < 192) {
        int c = tid / 6, ql = tid - c * 6;
        float accv[4] = {pbv[4 * ql + 0], pbv[4 * ql + 1], pbv[4 * ql + 2], pbv[4 * ql + 3]};
        #pragma unroll
        for (int lp = 0; lp < 24; lp += 2) {
            float pv0 = pbuff[c * 25 + lp];
            float pv1 = pbuff[c * 25 + lp + 1];
            #pragma unroll
            for (int e = 0; e < 4; e++) {
                uint32_t u = *(const uint32_t*)&pwh[(4 * ql + e) * 28 + lp];
                accv[e] += pv0 * __uint_as_float(u << 16) + pv1 * __uint_as_float(u & 0xffff0000u);
            }
        }
        float4* op = (float4*)(out + (size_t)b * (DD * NPOS) + (size_t)c * NPOS + 8 * LL);
        float4 xa = op[ql];
        float4 r;
        r.x = xa.x - accv[0]; r.y = xa.y - accv[1]; r.z = xa.z - accv[2]; r.w = xa.w - accv[3];
        op[ql] = r;
    }
}

extern "C" void kernel_launch(void* const* d_in, const int* in_sizes, int n_in,
                              void* d_out, int out_size, void* d_ws, size_t ws_size,
                              hipStream_t stream) {
    const float* x        = (const float*)d_in[0];
    const float* ln_g     = (const float*)d_in[1];
    const float* ln_b     = (const float*)d_in[2];
    const float* rp_w1    = (const float*)d_in[3];
    const float* rp_b1    = (const float*)d_in[4];
    const float* rp_w2    = (const float*)d_in[5];
    const float* rp_b2    = (const float*)d_in[6];
    const float* W_causal = (const float*)d_in[7];
    const float* mask_w   = (const float*)d_in[8];
    const float* mask_b   = (const float*)d_in[9];
    const float* val_w1   = (const float*)d_in[10];
    const float* val_b1   = (const float*)d_in[11];
    const float* val_w2   = (const float*)d_in[12];
    const float* val_b2   = (const float*)d_in[13];
    const float* fuse_g   = (const float*)d_in[14];
    const float* q_w      = (const float*)d_in[15];
    const float* q_b      = (const float*)d_in[16];
    const float* k_w      = (const float*)d_in[17];
    const float* k_b      = (const float*)d_in[18];
    const float* v_w      = (const float*)d_in[19];
    const float* v_b      = (const float*)d_in[20];
    const float* m_w      = (const float*)d_in[21];
    const float* m_b      = (const float*)d_in[22];
    const float* W_logit  = (const float*)d_in[23];
    const float* W_ctx    = (const float*)d_in[24];
    const float* rel_pb   = (const float*)d_in[25];
    const float* pre_pr   = (const float*)d_in[26];
    const float* conv_w   = (const float*)d_in[27];
    const float* conv_b   = (const float*)d_in[28];
    const float* p_w      = (const float*)d_in[29];
    const float* p_b      = (const float*)d_in[30];
    float* out = (float*)d_out;

    int B = in_sizes[0] / (DD * NPOS);

    float* ws = (float*)d_ws;
    float* sp = ws + 8192;            // B*32 sums, then overwritten with g*delta
    float* sq = sp + (size_t)B * 32;  // B*32 sum-of-squares

    hipLaunchKernelGGL(k0_prep, dim3(1), dim3(1024), 0, stream,
                       W_causal, W_logit, rel_pb, q_w, k_w, v_w, m_w, ws);
    hipLaunchKernelGGL(k1a, dim3(B), dim3(256), 0, stream, x, sp, sq);
    hipLaunchKernelGGL(k1b, dim3(B / 64), dim3(64), 0, stream,
                       ln_g, ln_b, rp_w1, rp_b1, rp_w2, rp_b2,
                       mask_w, mask_b, val_w1, val_b1, val_w2, val_b2,
                       fuse_g, ws, sp, sq);
    hipLaunchKernelGGL(k2_attn, dim3(B * TT), dim3(256), 0, stream,
                       x, ws, sp, q_b, k_b, v_b, m_b, W_ctx, out);
    hipLaunchKernelGGL(k3_pred, dim3(B), dim3(256), 0, stream,
                       pre_pr, conv_w, conv_b, p_w, p_b, out);
}